// Round 1
// baseline (206.037 us; speedup 1.0000x reference)
//
#include <hip/hip_runtime.h>

// Scatter-permute: out[expert_offsets[expert_idx[t]] + slot_idx[t], :] = token_hidden[t, :]
// T=65536 tokens, D=2048 f32. rows form a bijection over [0,T) -> every output
// row is written exactly once, so no zero-init of d_out is required.

__global__ void __launch_bounds__(256)
scatter_rows_kernel(const float4* __restrict__ src,
                    const int* __restrict__ expert_idx,
                    const int* __restrict__ slot_idx,
                    const int* __restrict__ expert_offsets,
                    float4* __restrict__ dst,
                    int d4)  // D/4 float4 elements per row
{
    const int t = blockIdx.x;
    // Wave-uniform index loads (blockIdx.x is scalar) -> scalar cache.
    const int row = expert_offsets[expert_idx[t]] + slot_idx[t];

    const float4* s = src + (size_t)t   * (size_t)d4;
    float4*       d = dst + (size_t)row * (size_t)d4;

    // d4 = 512, blockDim = 256 -> 2 fully-coalesced float4 per lane.
    for (int i = threadIdx.x; i < d4; i += blockDim.x) {
        d[i] = s[i];
    }
}

extern "C" void kernel_launch(void* const* d_in, const int* in_sizes, int n_in,
                              void* d_out, int out_size, void* d_ws, size_t ws_size,
                              hipStream_t stream) {
    const float* token_hidden   = (const float*)d_in[0];
    const int*   expert_idx     = (const int*)  d_in[1];
    const int*   slot_idx       = (const int*)  d_in[2];
    const int*   expert_offsets = (const int*)  d_in[3];
    // d_in[4] is num_rows (scalar), == T here.

    const int T = in_sizes[1];            // 65536 tokens
    const int D = in_sizes[0] / T;        // 2048 hidden
    const int d4 = D / 4;                 // 512 float4 per row

    float* out = (float*)d_out;

    scatter_rows_kernel<<<T, 256, 0, stream>>>(
        (const float4*)token_hidden, expert_idx, slot_idx, expert_offsets,
        (float4*)out, d4);
}